// Round 1
// baseline (1993.251 us; speedup 1.0000x reference)
//
#include <hip/hip_runtime.h>

#define BATCH 4
#define C 256
#define HW 4096
#define CHW (C*HW)            // 1048576 floats per batch per tensor
#define CPG 8                 // channels per group (C/32)
#define GELEMS (CPG*HW)       // 32768 elements per group (contiguous)

#define NEG_BIG (-3.0e38f)

// ---------------- GroupNorm: one block per (batch, group) ----------------
__global__ __launch_bounds__(256) void gn_kernel(const float* __restrict__ x,
    const float* __restrict__ gw, const float* __restrict__ gb,
    float* __restrict__ h) {
  int blk = blockIdx.x;            // b*32 + g
  int g = blk & 31;
  const float4* x4 = (const float4*)(x + (size_t)blk * GELEMS);
  float4* h4 = (float4*)(h + (size_t)blk * GELEMS);
  int t = threadIdx.x;

  float s = 0.f, ss = 0.f;
  for (int i = t; i < GELEMS/4; i += 256) {
    float4 v = x4[i];
    s  += v.x + v.y + v.z + v.w;
    ss += v.x*v.x + v.y*v.y + v.z*v.z + v.w*v.w;
  }
  #pragma unroll
  for (int off = 32; off > 0; off >>= 1) {
    s  += __shfl_down(s,  off, 64);
    ss += __shfl_down(ss, off, 64);
  }
  __shared__ float rs[4], rss[4];
  __shared__ float smean, sinv;
  int wid = t >> 6;
  if ((t & 63) == 0) { rs[wid] = s; rss[wid] = ss; }
  __syncthreads();
  if (t == 0) {
    float S  = rs[0] + rs[1] + rs[2] + rs[3];
    float SS = rss[0] + rss[1] + rss[2] + rss[3];
    float mean = S / (float)GELEMS;
    float var  = SS / (float)GELEMS - mean * mean;
    smean = mean;
    sinv  = rsqrtf(var + 1e-5f);
  }
  __syncthreads();
  float mean = smean, inv = sinv;
  for (int i = t; i < GELEMS/4; i += 256) {
    float4 v = x4[i];
    int cc = i >> 10;              // local channel 0..7 (4096 floats per channel)
    float w  = gw[g*CPG + cc];
    float bb = gb[g*CPG + cc];
    float4 o;
    o.x = (v.x - mean) * inv * w + bb;
    o.y = (v.y - mean) * inv * w + bb;
    o.z = (v.z - mean) * inv * w + bb;
    o.w = (v.w - mean) * inv * w + bb;
    h4[i] = o;
  }
}

// ---------------- fused QKV 1x1 conv: out[b][o][s] = bias + sum_c W[o][c]*h[b][c][s]
// block: (s_chunk of 512, o_tile of 8, b). thread: 2 spatial positions.
__global__ __launch_bounds__(256) void qkv_kernel(const float* __restrict__ h,
    const float* __restrict__ wq, const float* __restrict__ bq,
    const float* __restrict__ wk, const float* __restrict__ bk,
    const float* __restrict__ wv, const float* __restrict__ bv,
    float* __restrict__ q, float* __restrict__ k, float* __restrict__ v) {
  int sc = blockIdx.x, ot = blockIdx.y, b = blockIdx.z;
  int o0 = ot * 8, s0 = sc * 512, t = threadIdx.x;
  const float* hb = h + (size_t)b * CHW;
  int s1 = s0 + t, s2 = s1 + 256;
  float aq[8][2] = {}, ak[8][2] = {}, av[8][2] = {};
  for (int c = 0; c < C; ++c) {
    float h1 = hb[(size_t)c * HW + s1];
    float h2 = hb[(size_t)c * HW + s2];
    #pragma unroll
    for (int i = 0; i < 8; ++i) {
      float wqv = wq[(o0+i)*C + c];
      float wkv = wk[(o0+i)*C + c];
      float wvv = wv[(o0+i)*C + c];
      aq[i][0] += wqv*h1; aq[i][1] += wqv*h2;
      ak[i][0] += wkv*h1; ak[i][1] += wkv*h2;
      av[i][0] += wvv*h1; av[i][1] += wvv*h2;
    }
  }
  #pragma unroll
  for (int i = 0; i < 8; ++i) {
    size_t off = (size_t)b * CHW + (size_t)(o0+i) * HW;
    q[off+s1] = aq[i][0] + bq[o0+i];  q[off+s2] = aq[i][1] + bq[o0+i];
    k[off+s1] = ak[i][0] + bk[o0+i];  k[off+s2] = ak[i][1] + bk[o0+i];
    v[off+s1] = av[i][0] + bv[o0+i];  v[off+s2] = av[i][1] + bv[o0+i];
  }
}

// ---------------- flash attention ----------------
// Q_r, V_r are the (HW, C) raw-reshape views of the (C, HW) conv outputs =
// simply linear memory (row n = 256 consecutive floats). K stays (C, HW).
// Block: 16 query rows. Online softmax over 64 chunks of 64 keys.
// Output written TRANSPOSED as (C, HW) so the proj kernel reads coalesced.
__global__ __launch_bounds__(256) void att_kernel(const float* __restrict__ q,
    const float* __restrict__ k, const float* __restrict__ v,
    float* __restrict__ o) {
  int nt = blockIdx.x, b = blockIdx.y;
  int n0 = nt * 16;
  int t = threadIdx.x;
  __shared__ float qt[16][260];    // q tile, later reused to stage output
  __shared__ float S[16][65];      // score chunk (padded: row-stat loops conflict-free)
  __shared__ float mrow[16], lrow[16], arow[16];
  const float* qb = q + (size_t)b * CHW;
  const float* kb = k + (size_t)b * CHW;
  const float* vb = v + (size_t)b * CHW;

  for (int i = t; i < 1024; i += 256) {
    int r = i >> 6, c4 = (i & 63) * 4;
    *(float4*)&qt[r][c4] = *(const float4*)&qb[(size_t)(n0 + r) * C + c4];
  }
  if (t < 16) { mrow[t] = NEG_BIG; lrow[t] = 0.f; }
  int mm = t & 63;
  int rg = t >> 6;                 // wave id = row group (rows rg*4..rg*4+3)
  int c0 = (t & 63) * 4;           // PV column ownership
  float o_reg[4][4] = {};
  __syncthreads();

  for (int mc = 0; mc < 64; ++mc) {
    int m0 = mc * 64;
    // ---- S chunk = Qtile @ K[:, m0:m0+64] * C^-0.5 ----
    float acc[4] = {0.f, 0.f, 0.f, 0.f};
    const float* kp = kb + m0 + mm;
    for (int c = 0; c < C; c += 4) {
      float k0 = kp[(size_t)(c+0) * HW];
      float k1 = kp[(size_t)(c+1) * HW];
      float k2 = kp[(size_t)(c+2) * HW];
      float k3 = kp[(size_t)(c+3) * HW];
      #pragma unroll
      for (int j = 0; j < 4; ++j) {
        float4 qv = *(const float4*)&qt[rg*4 + j][c];
        acc[j] += qv.x*k0 + qv.y*k1 + qv.z*k2 + qv.w*k3;
      }
    }
    #pragma unroll
    for (int j = 0; j < 4; ++j) S[rg*4 + j][mm] = acc[j] * 0.0625f;
    __syncthreads();
    // ---- row max / alpha ----
    if (t < 16) {
      float mx = NEG_BIG;
      for (int m2 = 0; m2 < 64; ++m2) mx = fmaxf(mx, S[t][m2]);
      float mn = fmaxf(mrow[t], mx);
      arow[t] = __expf(mrow[t] - mn);
      mrow[t] = mn;
    }
    __syncthreads();
    // ---- exp in place ----
    #pragma unroll
    for (int j = 0; j < 4; ++j) {
      int r = rg*4 + j;
      S[r][mm] = __expf(S[r][mm] - mrow[r]);
    }
    __syncthreads();
    // ---- row sum (concurrent with PV; lrow not read until loop-end barrier) ----
    if (t < 16) {
      float sm = 0.f;
      for (int m2 = 0; m2 < 64; ++m2) sm += S[t][m2];
      lrow[t] = lrow[t] * arow[t] + sm;
    }
    // ---- PV: o += P_chunk @ V_chunk ----
    #pragma unroll
    for (int j = 0; j < 4; ++j) {
      float a = arow[rg*4 + j];
      #pragma unroll
      for (int i = 0; i < 4; ++i) o_reg[j][i] *= a;
    }
    for (int m2 = 0; m2 < 64; ++m2) {
      float4 vv = *(const float4*)&vb[(size_t)(m0 + m2) * C + c0];
      #pragma unroll
      for (int j = 0; j < 4; ++j) {
        float p = S[rg*4 + j][m2];
        o_reg[j][0] += p * vv.x; o_reg[j][1] += p * vv.y;
        o_reg[j][2] += p * vv.z; o_reg[j][3] += p * vv.w;
      }
    }
    __syncthreads();
  }

  // ---- epilogue: normalize, bounce through LDS, write transposed (C, HW) ----
  #pragma unroll
  for (int j = 0; j < 4; ++j) {
    float invl = 1.f / lrow[rg*4 + j];
    float4 ov;
    ov.x = o_reg[j][0] * invl; ov.y = o_reg[j][1] * invl;
    ov.z = o_reg[j][2] * invl; ov.w = o_reg[j][3] * invl;
    *(float4*)&qt[rg*4 + j][c0] = ov;
  }
  __syncthreads();
  float* ob = o + (size_t)b * CHW;
  for (int rep = 0; rep < 16; ++rep) {
    int c  = rep * 16 + (t >> 4);
    int nl = t & 15;
    ob[(size_t)c * HW + n0 + nl] = qt[nl][c];
  }
}

// ---------------- proj 1x1 conv + bias + residual ----------------
__global__ __launch_bounds__(256) void proj_kernel(const float* __restrict__ a,
    const float* __restrict__ wp, const float* __restrict__ bp,
    const float* __restrict__ x, float* __restrict__ out) {
  int sc = blockIdx.x, ot = blockIdx.y, b = blockIdx.z;
  int o0 = ot * 8, s0 = sc * 512, t = threadIdx.x;
  const float* ab = a + (size_t)b * CHW;
  int s1 = s0 + t, s2 = s1 + 256;
  float ac[8][2] = {};
  for (int c = 0; c < C; ++c) {
    float a1 = ab[(size_t)c * HW + s1];
    float a2 = ab[(size_t)c * HW + s2];
    #pragma unroll
    for (int i = 0; i < 8; ++i) {
      float w = wp[(o0+i)*C + c];
      ac[i][0] += w * a1; ac[i][1] += w * a2;
    }
  }
  #pragma unroll
  for (int i = 0; i < 8; ++i) {
    size_t off = (size_t)b * CHW + (size_t)(o0+i) * HW;
    out[off+s1] = x[off+s1] + bp[o0+i] + ac[i][0];
    out[off+s2] = x[off+s2] + bp[o0+i] + ac[i][1];
  }
}

extern "C" void kernel_launch(void* const* d_in, const int* in_sizes, int n_in,
                              void* d_out, int out_size, void* d_ws, size_t ws_size,
                              hipStream_t stream) {
  const float* x  = (const float*)d_in[0];
  const float* gw = (const float*)d_in[1];
  const float* gb = (const float*)d_in[2];
  const float* wq = (const float*)d_in[3];
  const float* bq = (const float*)d_in[4];
  const float* wk = (const float*)d_in[5];
  const float* bk = (const float*)d_in[6];
  const float* wv = (const float*)d_in[7];
  const float* bv = (const float*)d_in[8];
  const float* wp = (const float*)d_in[9];
  const float* bp = (const float*)d_in[10];
  float* out = (float*)d_out;
  float* ws  = (float*)d_ws;

  float* h = ws;                          // 4*CHW floats (16 MiB)
  float* q = ws + (size_t)4 * CHW;
  float* k = ws + (size_t)8 * CHW;
  float* v = ws + (size_t)12 * CHW;
  float* attn = ws;                       // reuse h region (h dead after qkv)

  gn_kernel<<<dim3(128), dim3(256), 0, stream>>>(x, gw, gb, h);
  qkv_kernel<<<dim3(8, 32, 4), dim3(256), 0, stream>>>(h, wq, bq, wk, bk, wv, bv, q, k, v);
  att_kernel<<<dim3(256, 4), dim3(256), 0, stream>>>(q, k, v, attn);
  proj_kernel<<<dim3(8, 32, 4), dim3(256), 0, stream>>>(attn, wp, bp, x, out);
}

// Round 3
// 514.036 us; speedup vs baseline: 3.8776x; 3.8776x over previous
//
#include <hip/hip_runtime.h>

#define BATCH 4
#define C 256
#define HW 4096
#define CHW (C*HW)            // 1048576 elements per batch per tensor
#define CPG 8                 // channels per group (C/32)
#define GELEMS (CPG*HW)       // 32768 elements per group (contiguous)

#define NEG_BIG (-3.0e38f)

typedef __attribute__((ext_vector_type(8))) short short8;   // 8 bf16 = 4 VGPRs
typedef __attribute__((ext_vector_type(4))) float floatx4;  // MFMA C/D frag

__device__ __forceinline__ unsigned short f2bf(float x) {
  union { float f; unsigned int u; } v; v.f = x;
  unsigned int r = v.u + 0x7FFF + ((v.u >> 16) & 1);   // RNE
  return (unsigned short)(r >> 16);
}

// ---------------- GroupNorm: one block per (batch, group) ----------------
__global__ __launch_bounds__(256) void gn_kernel(const float* __restrict__ x,
    const float* __restrict__ gw, const float* __restrict__ gb,
    float* __restrict__ h) {
  int blk = blockIdx.x;            // b*32 + g
  int g = blk & 31;
  const float4* x4 = (const float4*)(x + (size_t)blk * GELEMS);
  float4* h4 = (float4*)(h + (size_t)blk * GELEMS);
  int t = threadIdx.x;

  float s = 0.f, ss = 0.f;
  for (int i = t; i < GELEMS/4; i += 256) {
    float4 v = x4[i];
    s  += v.x + v.y + v.z + v.w;
    ss += v.x*v.x + v.y*v.y + v.z*v.z + v.w*v.w;
  }
  #pragma unroll
  for (int off = 32; off > 0; off >>= 1) {
    s  += __shfl_down(s,  off, 64);
    ss += __shfl_down(ss, off, 64);
  }
  __shared__ float rs[4], rss[4];
  __shared__ float smean, sinv;
  int wid = t >> 6;
  if ((t & 63) == 0) { rs[wid] = s; rss[wid] = ss; }
  __syncthreads();
  if (t == 0) {
    float S  = rs[0] + rs[1] + rs[2] + rs[3];
    float SS = rss[0] + rss[1] + rss[2] + rss[3];
    float mean = S / (float)GELEMS;
    float var  = SS / (float)GELEMS - mean * mean;
    smean = mean;
    sinv  = rsqrtf(var + 1e-5f);
  }
  __syncthreads();
  float mean = smean, inv = sinv;
  for (int i = t; i < GELEMS/4; i += 256) {
    float4 v = x4[i];
    int cc = i >> 10;              // local channel 0..7
    float w  = gw[g*CPG + cc];
    float bb = gb[g*CPG + cc];
    float4 o;
    o.x = (v.x - mean) * inv * w + bb;
    o.y = (v.y - mean) * inv * w + bb;
    o.z = (v.z - mean) * inv * w + bb;
    o.w = (v.w - mean) * inv * w + bb;
    h4[i] = o;
  }
}

// ---------------- fused QKV 1x1 conv (fp32 out) ----------------
__global__ __launch_bounds__(256) void qkv_kernel(const float* __restrict__ h,
    const float* __restrict__ wq, const float* __restrict__ bq,
    const float* __restrict__ wk, const float* __restrict__ bk,
    const float* __restrict__ wv, const float* __restrict__ bv,
    float* __restrict__ q, float* __restrict__ k, float* __restrict__ v) {
  int sc = blockIdx.x, ot = blockIdx.y, b = blockIdx.z;
  int o0 = ot * 8, s0 = sc * 512, t = threadIdx.x;
  const float* hb = h + (size_t)b * CHW;
  int s1 = s0 + t, s2 = s1 + 256;
  float aq[8][2] = {}, ak[8][2] = {}, av[8][2] = {};
  for (int c = 0; c < C; ++c) {
    float h1 = hb[(size_t)c * HW + s1];
    float h2 = hb[(size_t)c * HW + s2];
    #pragma unroll
    for (int i = 0; i < 8; ++i) {
      float wqv = wq[(o0+i)*C + c];
      float wkv = wk[(o0+i)*C + c];
      float wvv = wv[(o0+i)*C + c];
      aq[i][0] += wqv*h1; aq[i][1] += wqv*h2;
      ak[i][0] += wkv*h1; ak[i][1] += wkv*h2;
      av[i][0] += wvv*h1; av[i][1] += wvv*h2;
    }
  }
  #pragma unroll
  for (int i = 0; i < 8; ++i) {
    size_t off = (size_t)b * CHW + (size_t)(o0+i) * HW;
    q[off+s1] = aq[i][0] + bq[o0+i];  q[off+s2] = aq[i][1] + bq[o0+i];
    k[off+s1] = ak[i][0] + bk[o0+i];  k[off+s2] = ak[i][1] + bk[o0+i];
    v[off+s1] = av[i][0] + bv[o0+i];  v[off+s2] = av[i][1] + bv[o0+i];
  }
}

// ---------------- fp32 -> bf16 flat cast ----------------
__global__ __launch_bounds__(256) void cast_bf16_kernel(const float* __restrict__ in,
    unsigned short* __restrict__ out) {
  size_t i = ((size_t)blockIdx.x * 256 + threadIdx.x) * 4;
  float4 v = *(const float4*)(in + i);
  ushort4 o;
  o.x = f2bf(v.x); o.y = f2bf(v.y); o.z = f2bf(v.z); o.w = f2bf(v.w);
  *(ushort4*)(out + i) = o;
}

// ---------------- generic tiled transpose + bf16 cast ----------------
// in: (R x Cc) fp32 per batch; out: (Cc x R) bf16 per batch.
__global__ __launch_bounds__(256) void transpose_cast_kernel(
    const float* __restrict__ in, unsigned short* __restrict__ out, int R, int Cc) {
  __shared__ float tile[64][65];
  const float* inb = in + (size_t)blockIdx.z * CHW;
  unsigned short* outb = out + (size_t)blockIdx.z * CHW;
  int r0 = blockIdx.y * 64, c0 = blockIdx.x * 64;
  int t = threadIdx.x;
  int tr = t >> 4, tc4 = (t & 15) * 4;
  #pragma unroll
  for (int p = 0; p < 4; ++p) {
    int row = p * 16 + tr;
    float4 v4 = *(const float4*)(inb + (size_t)(r0 + row) * Cc + c0 + tc4);
    tile[row][tc4+0] = v4.x; tile[row][tc4+1] = v4.y;
    tile[row][tc4+2] = v4.z; tile[row][tc4+3] = v4.w;
  }
  __syncthreads();
  #pragma unroll
  for (int p = 0; p < 4; ++p) {
    int j = p * 16 + tr;             // output row = input column
    ushort4 o4;
    o4.x = f2bf(tile[tc4+0][j]);
    o4.y = f2bf(tile[tc4+1][j]);
    o4.z = f2bf(tile[tc4+2][j]);
    o4.w = f2bf(tile[tc4+3][j]);
    *(ushort4*)(outb + (size_t)(c0 + j) * R + r0 + tc4) = o4;
  }
}

// ---------------- MFMA flash attention ----------------
// qb : (B, 4096, 256) bf16  Q_r rows (flat natural conv buffer, just cast)
// ktb: (B, 4096, 256) bf16  ktb[m][c] = K[c][m]
// vt : (B, 256, 4096) bf16  vt[c][m]  = V_r[m][c]
// ot : (B, 256, 4096) fp32  ot[c][n]  = O[n][c]   (transposed for proj)
#define BR 64
#define BC 64
#define KS_PAD 264   // bf16 row stride (256 + 8): bank-optimal b128 frag reads
#define PS_PAD 72    // bf16 row stride (64 + 8)

__global__ __launch_bounds__(256) void att_kernel(
    const unsigned short* __restrict__ qb,
    const unsigned short* __restrict__ ktb,
    const unsigned short* __restrict__ vt,
    float* __restrict__ ot) {
  __shared__ __align__(16) unsigned short Ks[BC * KS_PAD];
  __shared__ __align__(16) unsigned short Ps[BR * PS_PAD];
  __shared__ float arow_s[BR], lrow_s[BR];

  int t = threadIdx.x;
  int w = t >> 6;            // wave 0..3
  int lane = t & 63;
  int n16 = lane & 15;       // MFMA "col" lane
  int q8 = lane >> 4;        // quad 0..3

  int nt = blockIdx.x, b = blockIdx.y;
  int n0 = nt * BR;

  const unsigned short* qB = qb + (size_t)b * CHW;
  const unsigned short* kB = ktb + (size_t)b * CHW;
  const unsigned short* vB = vt + (size_t)b * CHW;

  // Q fragments in registers: wave w owns q rows [n0+w*16, n0+w*16+16)
  short8 qf[8];
  {
    const unsigned short* qp = qB + (size_t)(n0 + w*16 + n16) * 256 + q8 * 8;
    #pragma unroll
    for (int kt = 0; kt < 8; ++kt)
      qf[kt] = *(const short8*)(qp + kt * 32);
  }

  float mrow[4], lrow[4];    // row = w*16 + q8*4 + r (replicated across n16 lanes)
  #pragma unroll
  for (int r = 0; r < 4; ++r) { mrow[r] = NEG_BIG; lrow[r] = 0.f; }

  floatx4 oacc[4][4];        // [ct][qt]; O^T rows c = w*64+ct*16+q8*4+reg, col q = qt*16+n16
  #pragma unroll
  for (int i = 0; i < 4; ++i)
    #pragma unroll
    for (int j = 0; j < 4; ++j)
      oacc[i][j] = (floatx4){0.f, 0.f, 0.f, 0.f};

  for (int mc = 0; mc < HW / BC; ++mc) {
    int m0 = mc * BC;
    // ---- stage K chunk (64 rows x 256 bf16 = 2048 16B chunks, 32/row) ----
    #pragma unroll
    for (int i = 0; i < 8; ++i) {
      int f = i * 256 + t;
      int row = f >> 5, col8 = f & 31;
      short8 kv = *(const short8*)(kB + (size_t)(m0 + row) * 256 + col8 * 8);
      *(short8*)(&Ks[row * KS_PAD + col8 * 8]) = kv;
    }
    __syncthreads();

    // ---- S = Q·K^T  (per wave: 16 q x 64 m) ----
    floatx4 sacc[4];
    #pragma unroll
    for (int mt = 0; mt < 4; ++mt) sacc[mt] = (floatx4){0.f, 0.f, 0.f, 0.f};
    #pragma unroll
    for (int kt = 0; kt < 8; ++kt) {
      #pragma unroll
      for (int mt = 0; mt < 4; ++mt) {
        short8 bk = *(const short8*)(&Ks[(mt*16 + n16) * KS_PAD + kt*32 + q8*8]);
        sacc[mt] = __builtin_amdgcn_mfma_f32_16x16x32_bf16(qf[kt], bk, sacc[mt], 0, 0, 0);
      }
    }

    // ---- online softmax (rows live in 16-lane groups) ----
    float pj[4][4];            // [mt][r]
    float alpha[4];
    #pragma unroll
    for (int r = 0; r < 4; ++r) {
      float s0 = sacc[0][r] * 0.0625f, s1 = sacc[1][r] * 0.0625f;
      float s2 = sacc[2][r] * 0.0625f, s3 = sacc[3][r] * 0.0625f;
      float mx = fmaxf(fmaxf(s0, s1), fmaxf(s2, s3));
      mx = fmaxf(mx, __shfl_xor(mx, 1));
      mx = fmaxf(mx, __shfl_xor(mx, 2));
      mx = fmaxf(mx, __shfl_xor(mx, 4));
      mx = fmaxf(mx, __shfl_xor(mx, 8));
      float mn = fmaxf(mrow[r], mx);
      float al = __expf(mrow[r] - mn);
      mrow[r] = mn;
      float e0 = __expf(s0 - mn), e1 = __expf(s1 - mn);
      float e2 = __expf(s2 - mn), e3 = __expf(s3 - mn);
      float sm = e0 + e1 + e2 + e3;
      sm += __shfl_xor(sm, 1); sm += __shfl_xor(sm, 2);
      sm += __shfl_xor(sm, 4); sm += __shfl_xor(sm, 8);
      lrow[r] = lrow[r] * al + sm;
      alpha[r] = al;
      pj[0][r] = e0; pj[1][r] = e1; pj[2][r] = e2; pj[3][r] = e3;
    }
    if (n16 == 0) {
      #pragma unroll
      for (int r = 0; r < 4; ++r) arow_s[w*16 + q8*4 + r] = alpha[r];
    }
    #pragma unroll
    for (int mt = 0; mt < 4; ++mt)
      #pragma unroll
      for (int r = 0; r < 4; ++r)
        Ps[(w*16 + q8*4 + r) * PS_PAD + mt*16 + n16] = f2bf(pj[mt][r]);
    __syncthreads();

    // ---- rescale O^T accumulators by alpha of their q column ----
    float al_q[4];
    #pragma unroll
    for (int qt = 0; qt < 4; ++qt) al_q[qt] = arow_s[qt*16 + n16];
    #pragma unroll
    for (int ct = 0; ct < 4; ++ct)
      #pragma unroll
      for (int qt = 0; qt < 4; ++qt) {
        oacc[ct][qt][0] *= al_q[qt]; oacc[ct][qt][1] *= al_q[qt];
        oacc[ct][qt][2] *= al_q[qt]; oacc[ct][qt][3] *= al_q[qt];
      }

    // ---- O^T += V^T_chunk · P^T  (per wave: 64 c x 64 q) ----
    #pragma unroll
    for (int kt2 = 0; kt2 < 2; ++kt2) {
      short8 vf[4], pf[4];
      #pragma unroll
      for (int ct = 0; ct < 4; ++ct)
        vf[ct] = *(const short8*)(vB + (size_t)(w*64 + ct*16 + n16) * HW + m0 + kt2*32 + q8*8);
      #pragma unroll
      for (int qt = 0; qt < 4; ++qt)
        pf[qt] = *(const short8*)(&Ps[(qt*16 + n16) * PS_PAD + kt2*32 + q8*8]);
      #pragma unroll
      for (int ct = 0; ct < 4; ++ct)
        #pragma unroll
        for (int qt = 0; qt < 4; ++qt)
          oacc[ct][qt] = __builtin_amdgcn_mfma_f32_16x16x32_bf16(vf[ct], pf[qt], oacc[ct][qt], 0, 0, 0);
    }
  }

  // ---- epilogue: divide by l, write O^T (c, n) ----
  if (n16 == 0) {
    #pragma unroll
    for (int r = 0; r < 4; ++r) lrow_s[w*16 + q8*4 + r] = lrow[r];
  }
  __syncthreads();
  float linv[4];
  #pragma unroll
  for (int qt = 0; qt < 4; ++qt) linv[qt] = 1.f / lrow_s[qt*16 + n16];
  float* oB = ot + (size_t)b * CHW;
  #pragma unroll
  for (int ct = 0; ct < 4; ++ct)
    #pragma unroll
    for (int qt = 0; qt < 4; ++qt)
      #pragma unroll
      for (int r = 0; r < 4; ++r) {
        int c = w*64 + ct*16 + q8*4 + r;
        oB[(size_t)c * HW + n0 + qt*16 + n16] = oacc[ct][qt][r] * linv[qt];
      }
}

// ---------------- proj 1x1 conv + bias + residual ----------------
__global__ __launch_bounds__(256) void proj_kernel(const float* __restrict__ a,
    const float* __restrict__ wp, const float* __restrict__ bp,
    const float* __restrict__ x, float* __restrict__ out) {
  int sc = blockIdx.x, ot = blockIdx.y, b = blockIdx.z;
  int o0 = ot * 8, s0 = sc * 512, t = threadIdx.x;
  const float* ab = a + (size_t)b * CHW;
  int s1 = s0 + t, s2 = s1 + 256;
  float ac[8][2] = {};
  for (int c = 0; c < C; ++c) {
    float a1 = ab[(size_t)c * HW + s1];
    float a2 = ab[(size_t)c * HW + s2];
    #pragma unroll
    for (int i = 0; i < 8; ++i) {
      float w = wp[(o0+i)*C + c];
      ac[i][0] += w * a1; ac[i][1] += w * a2;
    }
  }
  #pragma unroll
  for (int i = 0; i < 8; ++i) {
    size_t off = (size_t)b * CHW + (size_t)(o0+i) * HW;
    out[off+s1] = x[off+s1] + bp[o0+i] + ac[i][0];
    out[off+s2] = x[off+s2] + bp[o0+i] + ac[i][1];
  }
}

extern "C" void kernel_launch(void* const* d_in, const int* in_sizes, int n_in,
                              void* d_out, int out_size, void* d_ws, size_t ws_size,
                              hipStream_t stream) {
  const float* x  = (const float*)d_in[0];
  const float* gw = (const float*)d_in[1];
  const float* gb = (const float*)d_in[2];
  const float* wq = (const float*)d_in[3];
  const float* bq = (const float*)d_in[4];
  const float* wk = (const float*)d_in[5];
  const float* bk = (const float*)d_in[6];
  const float* wv = (const float*)d_in[7];
  const float* bv = (const float*)d_in[8];
  const float* wp = (const float*)d_in[9];
  const float* bp = (const float*)d_in[10];
  float* out = (float*)d_out;
  float* ws  = (float*)d_ws;

  float* h = ws;                              // region A: 4*CHW fp32 (16 MiB)
  float* q = ws + (size_t)4  * CHW;           // region B
  float* k = ws + (size_t)8  * CHW;           // region C
  float* v = ws + (size_t)12 * CHW;           // region D

  unsigned short* qbp  = (unsigned short*)ws;                    // region A lo (8 MiB)
  unsigned short* ktbp = (unsigned short*)ws + (size_t)4 * CHW;  // region A hi (8 MiB)
  unsigned short* vtp  = (unsigned short*)(ws + (size_t)4*CHW);  // region B lo (8 MiB)
  float* otp = ws + (size_t)8 * CHW;                             // region C (16 MiB)

  gn_kernel<<<dim3(128), dim3(256), 0, stream>>>(x, gw, gb, h);
  qkv_kernel<<<dim3(8, 32, 4), dim3(256), 0, stream>>>(h, wq, bq, wk, bk, wv, bv, q, k, v);
  cast_bf16_kernel<<<dim3(4096), dim3(256), 0, stream>>>(q, qbp);
  transpose_cast_kernel<<<dim3(64, 4, 4), dim3(256), 0, stream>>>(k, ktbp, 256, 4096);
  transpose_cast_kernel<<<dim3(4, 64, 4), dim3(256), 0, stream>>>(v, vtp, 4096, 256);
  att_kernel<<<dim3(64, 4), dim3(256), 0, stream>>>(qbp, ktbp, vtp, otp);
  proj_kernel<<<dim3(8, 32, 4), dim3(256), 0, stream>>>(otp, wp, bp, x, out);
}